// Round 1
// baseline (1613.495 us; speedup 1.0000x reference)
//
#include <hip/hip_runtime.h>
#include <math.h>

// GINE GNN: 3x [fused edge-linear + gather + relu + segment-sum] + MLP GEMMs + sigmoid head.
// Strategy: build CSR (by dst) on device each call; aggregation is atomic-free gather,
// edge-linear recomputed in registers (cheaper than materializing [E,128] through HBM).

#define BLK 256

// ---------------- CSR build ----------------

// edge_index may be int64 (reference says so) or int32 (JAX x64 disabled). Detect:
// int64 little-endian => odd 32-bit words are all 0 (values < 2^31). int32 => random.
__global__ void detect_kernel(const unsigned int* __restrict__ ei, int* __restrict__ flag) {
    int t = blockIdx.x * blockDim.x + threadIdx.x;
    if (t < 1024) {
        if (ei[2 * t + 1] != 0u) atomicOr(flag, 1);  // nonzero odd word => int32 mode
    }
}

__global__ void convert_kernel(const int* __restrict__ ei32, const long long* __restrict__ ei64,
                               const int* __restrict__ flag, int E,
                               int* __restrict__ src, int* __restrict__ dst) {
    int e = blockIdx.x * blockDim.x + threadIdx.x;
    if (e >= E) return;
    if (*flag) { src[e] = ei32[e]; dst[e] = ei32[E + e]; }
    else       { src[e] = (int)ei64[e]; dst[e] = (int)ei64[E + e]; }
}

__global__ void hist_kernel(const int* __restrict__ dst, int E, int* __restrict__ counts) {
    int e = blockIdx.x * blockDim.x + threadIdx.x;
    if (e < E) atomicAdd(&counts[dst[e]], 1);
}

// single-block scan: 256 threads, each owns a contiguous chunk
__global__ void scan_kernel(const int* __restrict__ counts, int* __restrict__ offsets, int n) {
    __shared__ int tsum[256];
    __shared__ int texcl[256];
    int t = threadIdx.x;
    int chunk = (n + 255) >> 8;
    int b = t * chunk, e = min(b + chunk, n);
    int s = 0;
    for (int i = b; i < e; i++) s += counts[i];
    tsum[t] = s;
    __syncthreads();
    if (t == 0) {
        int run = 0;
        for (int i = 0; i < 256; i++) { texcl[i] = run; run += tsum[i]; }
        offsets[n] = run;  // == E
    }
    __syncthreads();
    int run = texcl[t];
    for (int i = b; i < e; i++) { offsets[i] = run; run += counts[i]; }
}

__global__ void scatter_kernel(const int* __restrict__ src, const int* __restrict__ dst,
                               const int* __restrict__ offsets, int* __restrict__ cursor,
                               int2* __restrict__ meta, int E) {
    int e = blockIdx.x * blockDim.x + threadIdx.x;
    if (e >= E) return;
    int d = dst[e];
    int pos = offsets[d] + atomicAdd(&cursor[d], 1);
    meta[pos] = make_int2(src[e], e);   // (src node, edge id)
}

// ---------------- fused aggregation ----------------
// h[node] = x[node] + sum_{e: dst=node} relu( x[src_e] + edge_attr[e] @ We + be )
// One wave per node. Lane owns C = D/64 contiguous channels; We columns live in VGPRs.
template <int D>
__global__ __launch_bounds__(256) void aggregate_kernel(
    const float* __restrict__ x, const float* __restrict__ ea,
    const float* __restrict__ We, const float* __restrict__ be,
    const int* __restrict__ offsets, const int2* __restrict__ meta,
    float* __restrict__ h, int n) {
    constexpr int C = D / 64;
    int lane = threadIdx.x & 63;
    int node = blockIdx.x * 4 + (threadIdx.x >> 6);
    if (node >= n) return;
    int c0 = lane * C;

    float w[16][C];
#pragma unroll
    for (int k = 0; k < 16; k++)
#pragma unroll
        for (int j = 0; j < C; j++) w[k][j] = We[k * D + c0 + j];
    float bias[C], acc[C];
#pragma unroll
    for (int j = 0; j < C; j++) {
        bias[j] = be[c0 + j];
        acc[j] = x[(size_t)node * D + c0 + j];
    }
    int p = offsets[node], pe = offsets[node + 1];
    for (; p < pe; p++) {
        int2 m = meta[p];
        const float4* eap = (const float4*)(ea + (size_t)m.y * 16);
        float4 e0 = eap[0], e1 = eap[1], e2 = eap[2], e3 = eap[3];
        const float* xs = x + (size_t)m.x * D + c0;
        float ev[16] = {e0.x, e0.y, e0.z, e0.w, e1.x, e1.y, e1.z, e1.w,
                        e2.x, e2.y, e2.z, e2.w, e3.x, e3.y, e3.z, e3.w};
#pragma unroll
        for (int j = 0; j < C; j++) {
            float mv = xs[j] + bias[j];
#pragma unroll
            for (int k = 0; k < 16; k++) mv = fmaf(ev[k], w[k][j], mv);
            acc[j] += fmaxf(mv, 0.f);
        }
    }
#pragma unroll
    for (int j = 0; j < C; j++) h[(size_t)node * D + c0 + j] = acc[j];
}

// ---------------- fp32 GEMM: C[n,128] = relu(A[n,K] @ B[K,128] + bias) ----------------
// 64x128 tile per block, 256 threads, 8x4 accumulators per thread.
template <int K>
__global__ __launch_bounds__(256) void gemm_kernel(
    const float* __restrict__ A, const float* __restrict__ B,
    const float* __restrict__ bias, float* __restrict__ C, int n) {
    __shared__ __align__(16) float As[16][68];   // transposed A tile, padded
    __shared__ __align__(16) float Bs[16][128];
    int t = threadIdx.x;
    int row0 = blockIdx.x * 64;
    int tr = t >> 5, tc = t & 31;  // rows tr*8..+8, cols tc*4..+4
    float acc[8][4];
#pragma unroll
    for (int r = 0; r < 8; r++)
#pragma unroll
        for (int c = 0; c < 4; c++) acc[r][c] = 0.f;

    int lr = t >> 2, lk = (t & 3) * 4;   // A staging: row lr, k-offset lk
    int bk = t >> 4, bc = (t & 15) * 8;  // B staging

    for (int ks = 0; ks < K; ks += 16) {
        float4 a;
        int grow = row0 + lr;
        if (grow < n) a = *(const float4*)(A + (size_t)grow * K + ks + lk);
        else a = make_float4(0.f, 0.f, 0.f, 0.f);
        As[lk + 0][lr] = a.x; As[lk + 1][lr] = a.y;
        As[lk + 2][lr] = a.z; As[lk + 3][lr] = a.w;

        const float4* bp = (const float4*)(B + (size_t)(ks + bk) * 128 + bc);
        float4 b0 = bp[0], b1 = bp[1];
        *(float4*)&Bs[bk][bc] = b0;
        *(float4*)&Bs[bk][bc + 4] = b1;
        __syncthreads();
#pragma unroll
        for (int kk = 0; kk < 16; kk++) {
            float4 a0 = *(const float4*)&As[kk][tr * 8];
            float4 a1 = *(const float4*)&As[kk][tr * 8 + 4];
            float4 bv = *(const float4*)&Bs[kk][tc * 4];
            float ar[8] = {a0.x, a0.y, a0.z, a0.w, a1.x, a1.y, a1.z, a1.w};
            float bc4[4] = {bv.x, bv.y, bv.z, bv.w};
#pragma unroll
            for (int r = 0; r < 8; r++)
#pragma unroll
                for (int c = 0; c < 4; c++) acc[r][c] = fmaf(ar[r], bc4[c], acc[r][c]);
        }
        __syncthreads();
    }
    float4 bb = *(const float4*)(bias + tc * 4);
#pragma unroll
    for (int r = 0; r < 8; r++) {
        int grow = row0 + tr * 8 + r;
        if (grow < n) {
            float4 v;
            v.x = fmaxf(acc[r][0] + bb.x, 0.f);
            v.y = fmaxf(acc[r][1] + bb.y, 0.f);
            v.z = fmaxf(acc[r][2] + bb.z, 0.f);
            v.w = fmaxf(acc[r][3] + bb.w, 0.f);
            *(float4*)(C + (size_t)grow * 128 + tc * 4) = v;
        }
    }
}

// ---------------- head: out = sigmoid(x @ Wlin + blin) ----------------
__global__ __launch_bounds__(256) void final_kernel(
    const float* __restrict__ x, const float* __restrict__ Wlin,
    const float* __restrict__ blin, float* __restrict__ out, int n) {
    int lane = threadIdx.x & 63;
    int node = blockIdx.x * 4 + (threadIdx.x >> 6);
    if (node >= n) return;
    float2 w = *(const float2*)(Wlin + lane * 2);
    float2 xv = *(const float2*)(x + (size_t)node * 128 + lane * 2);
    float v = xv.x * w.x + xv.y * w.y;
#pragma unroll
    for (int off = 32; off; off >>= 1) v += __shfl_down(v, off, 64);
    if (lane == 0) out[node] = 1.f / (1.f + expf(-(v + blin[0])));
}

// ---------------- launch ----------------
extern "C" void kernel_launch(void* const* d_in, const int* in_sizes, int n_in,
                              void* d_out, int out_size, void* d_ws, size_t ws_size,
                              hipStream_t stream) {
    const float* x_in = (const float*)d_in[0];
    const void* ei    = d_in[1];
    const float* ea   = (const float*)d_in[2];
    const float* We[3]  = {(const float*)d_in[3], (const float*)d_in[9],  (const float*)d_in[15]};
    const float* be[3]  = {(const float*)d_in[4], (const float*)d_in[10], (const float*)d_in[16]};
    const float* W1[3]  = {(const float*)d_in[5], (const float*)d_in[11], (const float*)d_in[17]};
    const float* b1[3]  = {(const float*)d_in[6], (const float*)d_in[12], (const float*)d_in[18]};
    const float* W2[3]  = {(const float*)d_in[7], (const float*)d_in[13], (const float*)d_in[19]};
    const float* b2[3]  = {(const float*)d_in[8], (const float*)d_in[14], (const float*)d_in[20]};
    const float* Wlin = (const float*)d_in[21];
    const float* blin = (const float*)d_in[22];
    float* out = (float*)d_out;

    const int N = in_sizes[0] / 64;   // 50000
    const int E = in_sizes[1] / 2;    // 1.6M

    // workspace carve-up (256B aligned), total ~129 MB
    size_t off = 0;
    auto alloc = [&](size_t bytes) {
        void* p = (char*)d_ws + off;
        off += (bytes + 255) & ~(size_t)255;
        return p;
    };
    int*   flag    = (int*)alloc(4);
    int*   src32   = (int*)alloc((size_t)E * 4);
    int*   dst32   = (int*)alloc((size_t)E * 4);
    int*   counts  = (int*)alloc((size_t)N * 4);
    int*   offsets = (int*)alloc((size_t)(N + 1) * 4);
    int*   cursor  = (int*)alloc((size_t)N * 4);
    int2*  meta    = (int2*)alloc((size_t)E * 8);
    float* hbuf    = (float*)alloc((size_t)N * 128 * 4);
    float* y1      = (float*)alloc((size_t)N * 128 * 4);
    float* xA      = (float*)alloc((size_t)N * 128 * 4);
    float* xB      = (float*)alloc((size_t)N * 128 * 4);

    hipMemsetAsync(flag, 0, 4, stream);
    hipMemsetAsync(counts, 0, (size_t)N * 4, stream);
    hipMemsetAsync(cursor, 0, (size_t)N * 4, stream);

    int egrid = (E + BLK - 1) / BLK;
    detect_kernel<<<4, BLK, 0, stream>>>((const unsigned int*)ei, flag);
    convert_kernel<<<egrid, BLK, 0, stream>>>((const int*)ei, (const long long*)ei, flag, E, src32, dst32);
    hist_kernel<<<egrid, BLK, 0, stream>>>(dst32, E, counts);
    scan_kernel<<<1, BLK, 0, stream>>>(counts, offsets, N);
    scatter_kernel<<<egrid, BLK, 0, stream>>>(src32, dst32, offsets, cursor, meta, E);

    int ngrid4 = (N + 3) / 4;
    int ggrid  = (N + 63) / 64;

    // layer 0: d=64
    aggregate_kernel<64><<<ngrid4, BLK, 0, stream>>>(x_in, ea, We[0], be[0], offsets, meta, hbuf, N);
    gemm_kernel<64><<<ggrid, BLK, 0, stream>>>(hbuf, W1[0], b1[0], y1, N);
    gemm_kernel<128><<<ggrid, BLK, 0, stream>>>(y1, W2[0], b2[0], xA, N);
    // layer 1: d=128
    aggregate_kernel<128><<<ngrid4, BLK, 0, stream>>>(xA, ea, We[1], be[1], offsets, meta, hbuf, N);
    gemm_kernel<128><<<ggrid, BLK, 0, stream>>>(hbuf, W1[1], b1[1], y1, N);
    gemm_kernel<128><<<ggrid, BLK, 0, stream>>>(y1, W2[1], b2[1], xB, N);
    // layer 2: d=128
    aggregate_kernel<128><<<ngrid4, BLK, 0, stream>>>(xB, ea, We[2], be[2], offsets, meta, hbuf, N);
    gemm_kernel<128><<<ggrid, BLK, 0, stream>>>(hbuf, W1[2], b1[2], y1, N);
    gemm_kernel<128><<<ggrid, BLK, 0, stream>>>(y1, W2[2], b2[2], xA, N);

    final_kernel<<<ngrid4, BLK, 0, stream>>>(xA, Wlin, blin, out, N);
}

// Round 2
// 1014.893 us; speedup vs baseline: 1.5898x; 1.5898x over previous
//
#include <hip/hip_runtime.h>
#include <math.h>

// GINE GNN: 3x [fused edge-linear + gather + relu + segment-sum] + MLP GEMMs + sigmoid head.
// R2: CSR-permuted edge_attr (eap) + srcp removes the meta.y indirection;
//     readfirstlane(node) scalarizes uniform loads; edge loop unrolled x4
//     for 4 outstanding gather chains (R1 was latency-bound, VALUBusy 35%).

#define BLK 256

// ---------------- CSR build ----------------

// edge_index may be int64 (reference) or int32 (JAX x64 off). int64 LE => odd words all 0.
__global__ void detect_kernel(const unsigned int* __restrict__ ei, int* __restrict__ flag) {
    int t = blockIdx.x * blockDim.x + threadIdx.x;
    if (t < 1024) {
        if (ei[2 * t + 1] != 0u) atomicOr(flag, 1);  // nonzero odd word => int32 mode
    }
}

// convert + histogram fused
__global__ void convert_hist_kernel(const int* __restrict__ ei32, const long long* __restrict__ ei64,
                                    const int* __restrict__ flag, int E,
                                    int* __restrict__ src, int* __restrict__ dst,
                                    int* __restrict__ counts) {
    int e = blockIdx.x * blockDim.x + threadIdx.x;
    if (e >= E) return;
    int s, d;
    if (*flag) { s = ei32[e]; d = ei32[E + e]; }
    else       { s = (int)ei64[e]; d = (int)ei64[E + e]; }
    src[e] = s; dst[e] = d;
    atomicAdd(&counts[d], 1);
}

// single-block scan: 256 threads, each owns a contiguous chunk
__global__ void scan_kernel(const int* __restrict__ counts, int* __restrict__ offsets, int n) {
    __shared__ int tsum[256];
    __shared__ int texcl[256];
    int t = threadIdx.x;
    int chunk = (n + 255) >> 8;
    int b = t * chunk, e = min(b + chunk, n);
    int s = 0;
    for (int i = b; i < e; i++) s += counts[i];
    tsum[t] = s;
    __syncthreads();
    if (t == 0) {
        int run = 0;
        for (int i = 0; i < 256; i++) { texcl[i] = run; run += tsum[i]; }
        offsets[n] = run;  // == E
    }
    __syncthreads();
    int run = texcl[t];
    for (int i = b; i < e; i++) { offsets[i] = run; run += counts[i]; }
}

__global__ void scatter_kernel(const int* __restrict__ src, const int* __restrict__ dst,
                               const int* __restrict__ offsets, int* __restrict__ cursor,
                               int* __restrict__ srcp, int* __restrict__ perm, int E) {
    int e = blockIdx.x * blockDim.x + threadIdx.x;
    if (e >= E) return;
    int d = dst[e];
    int pos = offsets[d] + atomicAdd(&cursor[d], 1);
    srcp[pos] = src[e];
    perm[e] = pos;
}

// permute edge_attr rows into CSR order: thread per (edge, float4-chunk)
__global__ void permute_ea_kernel(const float4* __restrict__ ea4, const int* __restrict__ perm,
                                  float4* __restrict__ eap4, int E) {
    int t = blockIdx.x * blockDim.x + threadIdx.x;
    if (t >= E * 4) return;
    int e = t >> 2, c = t & 3;
    eap4[(size_t)perm[e] * 4 + c] = ea4[(size_t)e * 4 + c];
}

// ---------------- fused aggregation ----------------
// h[node] = x[node] + sum_{e: dst=node} relu( x[src_e] + ea_e @ We + be )
// One wave per node; lane owns C=D/64 channels; We columns in VGPRs; ea/srcp wave-uniform.
template <int D>
__global__ __launch_bounds__(256) void aggregate_kernel(
    const float* __restrict__ x, const float* __restrict__ eap,
    const int* __restrict__ srcp,
    const float* __restrict__ We, const float* __restrict__ be,
    const int* __restrict__ offsets,
    float* __restrict__ h, int n) {
    constexpr int C = D / 64;
    int lane = threadIdx.x & 63;
    int node = __builtin_amdgcn_readfirstlane(blockIdx.x * 4 + (threadIdx.x >> 6));
    if (node >= n) return;
    int c0 = lane * C;

    float w[16][C];
#pragma unroll
    for (int k = 0; k < 16; k++)
#pragma unroll
        for (int j = 0; j < C; j++) w[k][j] = We[k * D + c0 + j];
    float bias[C], acc[C];
#pragma unroll
    for (int j = 0; j < C; j++) {
        bias[j] = be[c0 + j];
        acc[j] = x[(size_t)node * D + c0 + j];
    }
    int p = offsets[node], pe = offsets[node + 1];

    // main loop: 4 edges per iteration, all 4 x-gathers issued before compute
    for (; p + 4 <= pe; p += 4) {
        int s0 = srcp[p], s1 = srcp[p + 1], s2 = srcp[p + 2], s3 = srcp[p + 3];
        float xv[4][C];
        {
            const float* r0 = x + (size_t)s0 * D + c0;
            const float* r1 = x + (size_t)s1 * D + c0;
            const float* r2 = x + (size_t)s2 * D + c0;
            const float* r3 = x + (size_t)s3 * D + c0;
            if constexpr (C == 2) {
                float2 t0 = *(const float2*)r0, t1 = *(const float2*)r1;
                float2 t2 = *(const float2*)r2, t3 = *(const float2*)r3;
                xv[0][0] = t0.x; xv[0][1] = t0.y; xv[1][0] = t1.x; xv[1][1] = t1.y;
                xv[2][0] = t2.x; xv[2][1] = t2.y; xv[3][0] = t3.x; xv[3][1] = t3.y;
            } else {
                xv[0][0] = *r0; xv[1][0] = *r1; xv[2][0] = *r2; xv[3][0] = *r3;
            }
        }
#pragma unroll
        for (int u = 0; u < 4; u++) {
            const float4* er = (const float4*)(eap + (size_t)(p + u) * 16);
            float4 e0 = er[0], e1 = er[1], e2 = er[2], e3 = er[3];
            float ev[16] = {e0.x, e0.y, e0.z, e0.w, e1.x, e1.y, e1.z, e1.w,
                            e2.x, e2.y, e2.z, e2.w, e3.x, e3.y, e3.z, e3.w};
#pragma unroll
            for (int j = 0; j < C; j++) {
                float mv = xv[u][j] + bias[j];
#pragma unroll
                for (int k = 0; k < 16; k++) mv = fmaf(ev[k], w[k][j], mv);
                acc[j] += fmaxf(mv, 0.f);
            }
        }
    }
    // tail
    for (; p < pe; p++) {
        int s = srcp[p];
        const float* xr = x + (size_t)s * D + c0;
        float xv[C];
        if constexpr (C == 2) { float2 t = *(const float2*)xr; xv[0] = t.x; xv[1] = t.y; }
        else xv[0] = *xr;
        const float4* er = (const float4*)(eap + (size_t)p * 16);
        float4 e0 = er[0], e1 = er[1], e2 = er[2], e3 = er[3];
        float ev[16] = {e0.x, e0.y, e0.z, e0.w, e1.x, e1.y, e1.z, e1.w,
                        e2.x, e2.y, e2.z, e2.w, e3.x, e3.y, e3.z, e3.w};
#pragma unroll
        for (int j = 0; j < C; j++) {
            float mv = xv[j] + bias[j];
#pragma unroll
            for (int k = 0; k < 16; k++) mv = fmaf(ev[k], w[k][j], mv);
            acc[j] += fmaxf(mv, 0.f);
        }
    }
#pragma unroll
    for (int j = 0; j < C; j++) h[(size_t)node * D + c0 + j] = acc[j];
}

// ---------------- fp32 GEMM: C[n,128] = relu(A[n,K] @ B[K,128] + bias) ----------------
// 64x128 tile per block, 256 threads, 8x4 accumulators per thread.
template <int K>
__global__ __launch_bounds__(256) void gemm_kernel(
    const float* __restrict__ A, const float* __restrict__ B,
    const float* __restrict__ bias, float* __restrict__ C, int n) {
    __shared__ __align__(16) float As[16][68];   // transposed A tile, padded
    __shared__ __align__(16) float Bs[16][128];
    int t = threadIdx.x;
    int row0 = blockIdx.x * 64;
    int tr = t >> 5, tc = t & 31;  // rows tr*8..+8, cols tc*4..+4
    float acc[8][4];
#pragma unroll
    for (int r = 0; r < 8; r++)
#pragma unroll
        for (int c = 0; c < 4; c++) acc[r][c] = 0.f;

    int lr = t >> 2, lk = (t & 3) * 4;   // A staging: row lr, k-offset lk
    int bk = t >> 4, bc = (t & 15) * 8;  // B staging

    for (int ks = 0; ks < K; ks += 16) {
        float4 a;
        int grow = row0 + lr;
        if (grow < n) a = *(const float4*)(A + (size_t)grow * K + ks + lk);
        else a = make_float4(0.f, 0.f, 0.f, 0.f);
        As[lk + 0][lr] = a.x; As[lk + 1][lr] = a.y;
        As[lk + 2][lr] = a.z; As[lk + 3][lr] = a.w;

        const float4* bp = (const float4*)(B + (size_t)(ks + bk) * 128 + bc);
        float4 b0 = bp[0], b1 = bp[1];
        *(float4*)&Bs[bk][bc] = b0;
        *(float4*)&Bs[bk][bc + 4] = b1;
        __syncthreads();
#pragma unroll
        for (int kk = 0; kk < 16; kk++) {
            float4 a0 = *(const float4*)&As[kk][tr * 8];
            float4 a1 = *(const float4*)&As[kk][tr * 8 + 4];
            float4 bv = *(const float4*)&Bs[kk][tc * 4];
            float ar[8] = {a0.x, a0.y, a0.z, a0.w, a1.x, a1.y, a1.z, a1.w};
            float bc4[4] = {bv.x, bv.y, bv.z, bv.w};
#pragma unroll
            for (int r = 0; r < 8; r++)
#pragma unroll
                for (int c = 0; c < 4; c++) acc[r][c] = fmaf(ar[r], bc4[c], acc[r][c]);
        }
        __syncthreads();
    }
    float4 bb = *(const float4*)(bias + tc * 4);
#pragma unroll
    for (int r = 0; r < 8; r++) {
        int grow = row0 + tr * 8 + r;
        if (grow < n) {
            float4 v;
            v.x = fmaxf(acc[r][0] + bb.x, 0.f);
            v.y = fmaxf(acc[r][1] + bb.y, 0.f);
            v.z = fmaxf(acc[r][2] + bb.z, 0.f);
            v.w = fmaxf(acc[r][3] + bb.w, 0.f);
            *(float4*)(C + (size_t)grow * 128 + tc * 4) = v;
        }
    }
}

// ---------------- head: out = sigmoid(x @ Wlin + blin) ----------------
__global__ __launch_bounds__(256) void final_kernel(
    const float* __restrict__ x, const float* __restrict__ Wlin,
    const float* __restrict__ blin, float* __restrict__ out, int n) {
    int lane = threadIdx.x & 63;
    int node = blockIdx.x * 4 + (threadIdx.x >> 6);
    if (node >= n) return;
    float2 w = *(const float2*)(Wlin + lane * 2);
    float2 xv = *(const float2*)(x + (size_t)node * 128 + lane * 2);
    float v = xv.x * w.x + xv.y * w.y;
#pragma unroll
    for (int off = 32; off; off >>= 1) v += __shfl_down(v, off, 64);
    if (lane == 0) out[node] = 1.f / (1.f + expf(-(v + blin[0])));
}

// ---------------- launch ----------------
extern "C" void kernel_launch(void* const* d_in, const int* in_sizes, int n_in,
                              void* d_out, int out_size, void* d_ws, size_t ws_size,
                              hipStream_t stream) {
    const float* x_in = (const float*)d_in[0];
    const void* ei    = d_in[1];
    const float* ea   = (const float*)d_in[2];
    const float* We[3]  = {(const float*)d_in[3], (const float*)d_in[9],  (const float*)d_in[15]};
    const float* be[3]  = {(const float*)d_in[4], (const float*)d_in[10], (const float*)d_in[16]};
    const float* W1[3]  = {(const float*)d_in[5], (const float*)d_in[11], (const float*)d_in[17]};
    const float* b1[3]  = {(const float*)d_in[6], (const float*)d_in[12], (const float*)d_in[18]};
    const float* W2[3]  = {(const float*)d_in[7], (const float*)d_in[13], (const float*)d_in[19]};
    const float* b2[3]  = {(const float*)d_in[8], (const float*)d_in[14], (const float*)d_in[20]};
    const float* Wlin = (const float*)d_in[21];
    const float* blin = (const float*)d_in[22];
    float* out = (float*)d_out;

    const int N = in_sizes[0] / 64;   // 50000
    const int E = in_sizes[1] / 2;    // 1.6M

    // workspace carve-up (256B aligned): ~206 MB
    size_t off = 0;
    auto alloc = [&](size_t bytes) {
        void* p = (char*)d_ws + off;
        off += (bytes + 255) & ~(size_t)255;
        return p;
    };
    int*   flag    = (int*)alloc(4);
    int*   src32   = (int*)alloc((size_t)E * 4);
    int*   dst32   = (int*)alloc((size_t)E * 4);
    int*   counts  = (int*)alloc((size_t)N * 4);
    int*   offsets = (int*)alloc((size_t)(N + 1) * 4);
    int*   cursor  = (int*)alloc((size_t)N * 4);
    int*   srcp    = (int*)alloc((size_t)E * 4);
    int*   perm    = (int*)alloc((size_t)E * 4);
    float* eap     = (float*)alloc((size_t)E * 16 * 4);
    float* bufA    = (float*)alloc((size_t)N * 128 * 4);
    float* bufB    = (float*)alloc((size_t)N * 128 * 4);
    float* bufC    = (float*)alloc((size_t)N * 128 * 4);

    hipMemsetAsync(flag, 0, 4, stream);
    hipMemsetAsync(counts, 0, (size_t)N * 4, stream);
    hipMemsetAsync(cursor, 0, (size_t)N * 4, stream);

    int egrid = (E + BLK - 1) / BLK;
    detect_kernel<<<4, BLK, 0, stream>>>((const unsigned int*)ei, flag);
    convert_hist_kernel<<<egrid, BLK, 0, stream>>>((const int*)ei, (const long long*)ei, flag, E,
                                                   src32, dst32, counts);
    scan_kernel<<<1, BLK, 0, stream>>>(counts, offsets, N);
    scatter_kernel<<<egrid, BLK, 0, stream>>>(src32, dst32, offsets, cursor, srcp, perm, E);
    permute_ea_kernel<<<(E * 4 + BLK - 1) / BLK, BLK, 0, stream>>>(
        (const float4*)ea, perm, (float4*)eap, E);

    int ngrid4 = (N + 3) / 4;
    int ggrid  = (N + 63) / 64;

    // 3-buffer rotation: agg(in->A); g1(A->B); g2(B->C); next agg reads C.
    // layer 0: d=64
    aggregate_kernel<64><<<ngrid4, BLK, 0, stream>>>(x_in, eap, srcp, We[0], be[0], offsets, bufA, N);
    gemm_kernel<64><<<ggrid, BLK, 0, stream>>>(bufA, W1[0], b1[0], bufB, N);
    gemm_kernel<128><<<ggrid, BLK, 0, stream>>>(bufB, W2[0], b2[0], bufC, N);
    // layer 1: d=128
    aggregate_kernel<128><<<ngrid4, BLK, 0, stream>>>(bufC, eap, srcp, We[1], be[1], offsets, bufA, N);
    gemm_kernel<128><<<ggrid, BLK, 0, stream>>>(bufA, W1[1], b1[1], bufB, N);
    gemm_kernel<128><<<ggrid, BLK, 0, stream>>>(bufB, W2[1], b2[1], bufC, N);
    // layer 2: d=128
    aggregate_kernel<128><<<ngrid4, BLK, 0, stream>>>(bufC, eap, srcp, We[2], be[2], offsets, bufA, N);
    gemm_kernel<128><<<ggrid, BLK, 0, stream>>>(bufA, W1[2], b1[2], bufB, N);
    gemm_kernel<128><<<ggrid, BLK, 0, stream>>>(bufB, W2[2], b2[2], bufC, N);

    final_kernel<<<ngrid4, BLK, 0, stream>>>(bufC, Wlin, blin, out, N);
}

// Round 3
// 987.590 us; speedup vs baseline: 1.6338x; 1.0276x over previous
//
#include <hip/hip_runtime.h>
#include <math.h>

// GINE GNN: 3x [fused edge-linear + gather + relu + segment-sum] + MLP GEMMs + sigmoid head.
// R3: v_pk_fma_f32 packed fp32 in the aggregate inner loop (R2 was VALU-bound at 76%);
//     scatter+ea-permute fused into one kernel (drops perm round-trip).

#define BLK 256

typedef __attribute__((ext_vector_type(2))) float f32x2;

__device__ inline f32x2 pk_fma(f32x2 a, f32x2 b, f32x2 c) {
    f32x2 d;
    asm("v_pk_fma_f32 %0, %1, %2, %3" : "=v"(d) : "v"(a), "v"(b), "v"(c));
    return d;
}

// ---------------- CSR build ----------------

// edge_index may be int64 (reference) or int32 (JAX x64 off). int64 LE => odd words all 0.
__global__ void detect_kernel(const unsigned int* __restrict__ ei, int* __restrict__ flag) {
    int t = blockIdx.x * blockDim.x + threadIdx.x;
    if (t < 1024) {
        if (ei[2 * t + 1] != 0u) atomicOr(flag, 1);  // nonzero odd word => int32 mode
    }
}

// convert + histogram fused
__global__ void convert_hist_kernel(const int* __restrict__ ei32, const long long* __restrict__ ei64,
                                    const int* __restrict__ flag, int E,
                                    int* __restrict__ src, int* __restrict__ dst,
                                    int* __restrict__ counts) {
    int e = blockIdx.x * blockDim.x + threadIdx.x;
    if (e >= E) return;
    int s, d;
    if (*flag) { s = ei32[e]; d = ei32[E + e]; }
    else       { s = (int)ei64[e]; d = (int)ei64[E + e]; }
    src[e] = s; dst[e] = d;
    atomicAdd(&counts[d], 1);
}

// single-block scan: 256 threads, each owns a contiguous chunk
__global__ void scan_kernel(const int* __restrict__ counts, int* __restrict__ offsets, int n) {
    __shared__ int tsum[256];
    __shared__ int texcl[256];
    int t = threadIdx.x;
    int chunk = (n + 255) >> 8;
    int b = t * chunk, e = min(b + chunk, n);
    int s = 0;
    for (int i = b; i < e; i++) s += counts[i];
    tsum[t] = s;
    __syncthreads();
    if (t == 0) {
        int run = 0;
        for (int i = 0; i < 256; i++) { texcl[i] = run; run += tsum[i]; }
        offsets[n] = run;  // == E
    }
    __syncthreads();
    int run = texcl[t];
    for (int i = b; i < e; i++) { offsets[i] = run; run += counts[i]; }
}

// scatter + edge_attr permute fused: place srcp and the ea row at CSR position
__global__ void scatter_ea_kernel(const int* __restrict__ src, const int* __restrict__ dst,
                                  const int* __restrict__ offsets, int* __restrict__ cursor,
                                  const float4* __restrict__ ea4,
                                  int* __restrict__ srcp, float4* __restrict__ eap4, int E) {
    int e = blockIdx.x * blockDim.x + threadIdx.x;
    if (e >= E) return;
    int d = dst[e];
    int pos = offsets[d] + atomicAdd(&cursor[d], 1);
    srcp[pos] = src[e];
    float4 a = ea4[(size_t)e * 4 + 0], b = ea4[(size_t)e * 4 + 1];
    float4 c = ea4[(size_t)e * 4 + 2], w = ea4[(size_t)e * 4 + 3];
    eap4[(size_t)pos * 4 + 0] = a;
    eap4[(size_t)pos * 4 + 1] = b;
    eap4[(size_t)pos * 4 + 2] = c;
    eap4[(size_t)pos * 4 + 3] = w;
}

// ---------------- fused aggregation ----------------
// h[node] = x[node] + sum_{e: dst=node} relu( x[src_e] + ea_e @ We + be )
// One wave per node; lane owns C=D/64 channels; edge-linear via v_pk_fma_f32
// over k-pairs (K=16 -> 8 pk_fma per channel).
template <int D>
__global__ __launch_bounds__(256) void aggregate_kernel(
    const float* __restrict__ x, const float* __restrict__ eap,
    const int* __restrict__ srcp,
    const float* __restrict__ We, const float* __restrict__ be,
    const int* __restrict__ offsets,
    float* __restrict__ h, int n) {
    constexpr int C = D / 64;
    int lane = threadIdx.x & 63;
    int node = __builtin_amdgcn_readfirstlane(blockIdx.x * 4 + (threadIdx.x >> 6));
    if (node >= n) return;
    int c0 = lane * C;

    // weights packed over k-pairs: wp[j][t] = {We[2t][c0+j], We[2t+1][c0+j]}
    f32x2 wp[C][8];
#pragma unroll
    for (int j = 0; j < C; j++)
#pragma unroll
        for (int t = 0; t < 8; t++) {
            f32x2 v; v.x = We[(2 * t) * D + c0 + j]; v.y = We[(2 * t + 1) * D + c0 + j];
            wp[j][t] = v;
        }
    float bias[C], acc[C];
#pragma unroll
    for (int j = 0; j < C; j++) {
        bias[j] = be[c0 + j];
        acc[j] = x[(size_t)node * D + c0 + j];
    }
    int p = offsets[node], pe = offsets[node + 1];

    // 4 edges per iteration, all 4 x-gathers issued before compute
    for (; p + 4 <= pe; p += 4) {
        int s0 = srcp[p], s1 = srcp[p + 1], s2 = srcp[p + 2], s3 = srcp[p + 3];
        float xv[4][C];
        {
            const float* r0 = x + (size_t)s0 * D + c0;
            const float* r1 = x + (size_t)s1 * D + c0;
            const float* r2 = x + (size_t)s2 * D + c0;
            const float* r3 = x + (size_t)s3 * D + c0;
            if constexpr (C == 2) {
                float2 t0 = *(const float2*)r0, t1 = *(const float2*)r1;
                float2 t2 = *(const float2*)r2, t3 = *(const float2*)r3;
                xv[0][0] = t0.x; xv[0][1] = t0.y; xv[1][0] = t1.x; xv[1][1] = t1.y;
                xv[2][0] = t2.x; xv[2][1] = t2.y; xv[3][0] = t3.x; xv[3][1] = t3.y;
            } else {
                xv[0][0] = *r0; xv[1][0] = *r1; xv[2][0] = *r2; xv[3][0] = *r3;
            }
        }
#pragma unroll
        for (int u = 0; u < 4; u++) {
            const float4* er = (const float4*)(eap + (size_t)(p + u) * 16);
            float4 e0 = er[0], e1 = er[1], e2 = er[2], e3 = er[3];
            f32x2 ev[8];
            ev[0].x = e0.x; ev[0].y = e0.y;  ev[1].x = e0.z; ev[1].y = e0.w;
            ev[2].x = e1.x; ev[2].y = e1.y;  ev[3].x = e1.z; ev[3].y = e1.w;
            ev[4].x = e2.x; ev[4].y = e2.y;  ev[5].x = e2.z; ev[5].y = e2.w;
            ev[6].x = e3.x; ev[6].y = e3.y;  ev[7].x = e3.z; ev[7].y = e3.w;
#pragma unroll
            for (int j = 0; j < C; j++) {
                f32x2 prod; prod.x = xv[u][j] + bias[j]; prod.y = 0.f;
#pragma unroll
                for (int t = 0; t < 8; t++) prod = pk_fma(ev[t], wp[j][t], prod);
                acc[j] += fmaxf(prod.x + prod.y, 0.f);
            }
        }
    }
    // tail
    for (; p < pe; p++) {
        int s = srcp[p];
        const float* xr = x + (size_t)s * D + c0;
        float xv[C];
        if constexpr (C == 2) { float2 t = *(const float2*)xr; xv[0] = t.x; xv[1] = t.y; }
        else xv[0] = *xr;
        const float4* er = (const float4*)(eap + (size_t)p * 16);
        float4 e0 = er[0], e1 = er[1], e2 = er[2], e3 = er[3];
        f32x2 ev[8];
        ev[0].x = e0.x; ev[0].y = e0.y;  ev[1].x = e0.z; ev[1].y = e0.w;
        ev[2].x = e1.x; ev[2].y = e1.y;  ev[3].x = e1.z; ev[3].y = e1.w;
        ev[4].x = e2.x; ev[4].y = e2.y;  ev[5].x = e2.z; ev[5].y = e2.w;
        ev[6].x = e3.x; ev[6].y = e3.y;  ev[7].x = e3.z; ev[7].y = e3.w;
#pragma unroll
        for (int j = 0; j < C; j++) {
            f32x2 prod; prod.x = xv[j] + bias[j]; prod.y = 0.f;
#pragma unroll
            for (int t = 0; t < 8; t++) prod = pk_fma(ev[t], wp[j][t], prod);
            acc[j] += fmaxf(prod.x + prod.y, 0.f);
        }
    }
#pragma unroll
    for (int j = 0; j < C; j++) h[(size_t)node * D + c0 + j] = acc[j];
}

// ---------------- fp32 GEMM: C[n,128] = relu(A[n,K] @ B[K,128] + bias) ----------------
// 64x128 tile per block, 256 threads, 8x4 accumulators per thread.
template <int K>
__global__ __launch_bounds__(256) void gemm_kernel(
    const float* __restrict__ A, const float* __restrict__ B,
    const float* __restrict__ bias, float* __restrict__ C, int n) {
    __shared__ __align__(16) float As[16][68];   // transposed A tile, padded
    __shared__ __align__(16) float Bs[16][128];
    int t = threadIdx.x;
    int row0 = blockIdx.x * 64;
    int tr = t >> 5, tc = t & 31;  // rows tr*8..+8, cols tc*4..+4
    float acc[8][4];
#pragma unroll
    for (int r = 0; r < 8; r++)
#pragma unroll
        for (int c = 0; c < 4; c++) acc[r][c] = 0.f;

    int lr = t >> 2, lk = (t & 3) * 4;   // A staging: row lr, k-offset lk
    int bk = t >> 4, bc = (t & 15) * 8;  // B staging

    for (int ks = 0; ks < K; ks += 16) {
        float4 a;
        int grow = row0 + lr;
        if (grow < n) a = *(const float4*)(A + (size_t)grow * K + ks + lk);
        else a = make_float4(0.f, 0.f, 0.f, 0.f);
        As[lk + 0][lr] = a.x; As[lk + 1][lr] = a.y;
        As[lk + 2][lr] = a.z; As[lk + 3][lr] = a.w;

        const float4* bp = (const float4*)(B + (size_t)(ks + bk) * 128 + bc);
        float4 b0 = bp[0], b1 = bp[1];
        *(float4*)&Bs[bk][bc] = b0;
        *(float4*)&Bs[bk][bc + 4] = b1;
        __syncthreads();
#pragma unroll
        for (int kk = 0; kk < 16; kk++) {
            float4 a0 = *(const float4*)&As[kk][tr * 8];
            float4 a1 = *(const float4*)&As[kk][tr * 8 + 4];
            float4 bv = *(const float4*)&Bs[kk][tc * 4];
            float ar[8] = {a0.x, a0.y, a0.z, a0.w, a1.x, a1.y, a1.z, a1.w};
            float bc4[4] = {bv.x, bv.y, bv.z, bv.w};
#pragma unroll
            for (int r = 0; r < 8; r++)
#pragma unroll
                for (int c = 0; c < 4; c++) acc[r][c] = fmaf(ar[r], bc4[c], acc[r][c]);
        }
        __syncthreads();
    }
    float4 bb = *(const float4*)(bias + tc * 4);
#pragma unroll
    for (int r = 0; r < 8; r++) {
        int grow = row0 + tr * 8 + r;
        if (grow < n) {
            float4 v;
            v.x = fmaxf(acc[r][0] + bb.x, 0.f);
            v.y = fmaxf(acc[r][1] + bb.y, 0.f);
            v.z = fmaxf(acc[r][2] + bb.z, 0.f);
            v.w = fmaxf(acc[r][3] + bb.w, 0.f);
            *(float4*)(C + (size_t)grow * 128 + tc * 4) = v;
        }
    }
}

// ---------------- head: out = sigmoid(x @ Wlin + blin) ----------------
__global__ __launch_bounds__(256) void final_kernel(
    const float* __restrict__ x, const float* __restrict__ Wlin,
    const float* __restrict__ blin, float* __restrict__ out, int n) {
    int lane = threadIdx.x & 63;
    int node = blockIdx.x * 4 + (threadIdx.x >> 6);
    if (node >= n) return;
    float2 w = *(const float2*)(Wlin + lane * 2);
    float2 xv = *(const float2*)(x + (size_t)node * 128 + lane * 2);
    float v = xv.x * w.x + xv.y * w.y;
#pragma unroll
    for (int off = 32; off; off >>= 1) v += __shfl_down(v, off, 64);
    if (lane == 0) out[node] = 1.f / (1.f + expf(-(v + blin[0])));
}

// ---------------- launch ----------------
extern "C" void kernel_launch(void* const* d_in, const int* in_sizes, int n_in,
                              void* d_out, int out_size, void* d_ws, size_t ws_size,
                              hipStream_t stream) {
    const float* x_in = (const float*)d_in[0];
    const void* ei    = d_in[1];
    const float* ea   = (const float*)d_in[2];
    const float* We[3]  = {(const float*)d_in[3], (const float*)d_in[9],  (const float*)d_in[15]};
    const float* be[3]  = {(const float*)d_in[4], (const float*)d_in[10], (const float*)d_in[16]};
    const float* W1[3]  = {(const float*)d_in[5], (const float*)d_in[11], (const float*)d_in[17]};
    const float* b1[3]  = {(const float*)d_in[6], (const float*)d_in[12], (const float*)d_in[18]};
    const float* W2[3]  = {(const float*)d_in[7], (const float*)d_in[13], (const float*)d_in[19]};
    const float* b2[3]  = {(const float*)d_in[8], (const float*)d_in[14], (const float*)d_in[20]};
    const float* Wlin = (const float*)d_in[21];
    const float* blin = (const float*)d_in[22];
    float* out = (float*)d_out;

    const int N = in_sizes[0] / 64;   // 50000
    const int E = in_sizes[1] / 2;    // 1.6M

    size_t off = 0;
    auto alloc = [&](size_t bytes) {
        void* p = (char*)d_ws + off;
        off += (bytes + 255) & ~(size_t)255;
        return p;
    };
    int*   flag    = (int*)alloc(4);
    int*   src32   = (int*)alloc((size_t)E * 4);
    int*   dst32   = (int*)alloc((size_t)E * 4);
    int*   counts  = (int*)alloc((size_t)N * 4);
    int*   offsets = (int*)alloc((size_t)(N + 1) * 4);
    int*   cursor  = (int*)alloc((size_t)N * 4);
    int*   srcp    = (int*)alloc((size_t)E * 4);
    float* eap     = (float*)alloc((size_t)E * 16 * 4);
    float* bufA    = (float*)alloc((size_t)N * 128 * 4);
    float* bufB    = (float*)alloc((size_t)N * 128 * 4);
    float* bufC    = (float*)alloc((size_t)N * 128 * 4);

    hipMemsetAsync(flag, 0, 4, stream);
    hipMemsetAsync(counts, 0, (size_t)N * 4, stream);
    hipMemsetAsync(cursor, 0, (size_t)N * 4, stream);

    int egrid = (E + BLK - 1) / BLK;
    detect_kernel<<<4, BLK, 0, stream>>>((const unsigned int*)ei, flag);
    convert_hist_kernel<<<egrid, BLK, 0, stream>>>((const int*)ei, (const long long*)ei, flag, E,
                                                   src32, dst32, counts);
    scan_kernel<<<1, BLK, 0, stream>>>(counts, offsets, N);
    scatter_ea_kernel<<<egrid, BLK, 0, stream>>>(src32, dst32, offsets, cursor,
                                                 (const float4*)ea, srcp, (float4*)eap, E);

    int ngrid4 = (N + 3) / 4;
    int ggrid  = (N + 63) / 64;

    // layer 0: d=64
    aggregate_kernel<64><<<ngrid4, BLK, 0, stream>>>(x_in, eap, srcp, We[0], be[0], offsets, bufA, N);
    gemm_kernel<64><<<ggrid, BLK, 0, stream>>>(bufA, W1[0], b1[0], bufB, N);
    gemm_kernel<128><<<ggrid, BLK, 0, stream>>>(bufB, W2[0], b2[0], bufC, N);
    // layer 1: d=128
    aggregate_kernel<128><<<ngrid4, BLK, 0, stream>>>(bufC, eap, srcp, We[1], be[1], offsets, bufA, N);
    gemm_kernel<128><<<ggrid, BLK, 0, stream>>>(bufA, W1[1], b1[1], bufB, N);
    gemm_kernel<128><<<ggrid, BLK, 0, stream>>>(bufB, W2[1], b2[1], bufC, N);
    // layer 2: d=128
    aggregate_kernel<128><<<ngrid4, BLK, 0, stream>>>(bufC, eap, srcp, We[2], be[2], offsets, bufA, N);
    gemm_kernel<128><<<ggrid, BLK, 0, stream>>>(bufA, W1[2], b1[2], bufB, N);
    gemm_kernel<128><<<ggrid, BLK, 0, stream>>>(bufB, W2[2], b2[2], bufC, N);

    final_kernel<<<ngrid4, BLK, 0, stream>>>(bufC, Wlin, blin, out, N);
}